// Round 4
// baseline (448.795 us; speedup 1.0000x reference)
//
#include <hip/hip_runtime.h>

typedef unsigned short u16;
typedef __attribute__((ext_vector_type(8))) short bf16x8;
typedef __attribute__((ext_vector_type(8))) _Float16 f16x8;
typedef __attribute__((ext_vector_type(4))) float f32x4;
typedef __attribute__((ext_vector_type(4))) unsigned short us4;
typedef __attribute__((ext_vector_type(4))) unsigned int u32x4;

#define DEV static __device__ __forceinline__

DEV u16 bf_trunc(float x){ return (u16)(__builtin_bit_cast(unsigned int, x) >> 16); }
DEV float bf_tof(u16 h){ unsigned int u = ((unsigned int)h) << 16; return __builtin_bit_cast(float, u); }
DEV u16 bf_rne(float x){
    unsigned int u = __builtin_bit_cast(unsigned int, x);
    return (u16)((u + 0x7fffu + ((u >> 16) & 1u)) >> 16);
}
DEV u16 f16_rne(float x){ _Float16 h = (_Float16)x; return __builtin_bit_cast(unsigned short, h); }
// packed f32x2 -> bf16x2 (RNE), lo = a, hi = b
DEV unsigned int cvtpk_bf16(float a, float b){
    unsigned int r;
    asm("v_cvt_pk_bf16_f32 %0, %1, %2" : "=v"(r) : "v"(a), "v"(b));
    return r;
}
// 2^x via hardware transcendental (v_exp_f32 computes 2^S0)
DEV float exp2_fast(float x){
    float r;
    asm("v_exp_f32 %0, %1" : "=v"(r) : "v"(x));
    return r;
}

#define QSCALE 11.541560327111707f   /* 8 * log2(e): scores come out in log2 domain */
#define DEFER_THR 11.0f              /* allow p up to 2^11 before rescaling (T13) */

// XOR swizzle on 16B column-blocks of a 64-col u16 tile: (r, col-chunk cb) -> r*64 + SW(r,cb)
#define SW(r,cb) ((((cb) ^ ((r)&7)))*8)

// ---------------- split fp32 -> hi/lo bf16 ----------------
__global__ __launch_bounds__(256) void k_split(const float4* __restrict__ in,
                                               u16* __restrict__ hi, u16* __restrict__ lo, int n4){
    int i = blockIdx.x*256 + threadIdx.x;
    if (i >= n4) return;
    float4 v = in[i];
    float vv[4] = {v.x, v.y, v.z, v.w};
    us4 h, l;
    #pragma unroll
    for (int j = 0; j < 4; ++j){
        u16 hs = bf_trunc(vv[j]);
        h[j] = hs;
        l[j] = bf_trunc(vv[j] - bf_tof(hs));
    }
    ((us4*)hi)[i] = h;
    ((us4*)lo)[i] = l;
}

// ---------------- qkv GEMM (split bf16; 128x128 tile) ----------------
// C[m][o] = sum_c x[m][c]*W[o][c], M=8192, O=2304, K=768.
// q,k tiles: 3-MFMA split. v tiles: single MFMA (bf16 storage bound anyway).
// Outputs: q fp16 pre-scaled by 8*log2e; k fp16; v bf16 transposed [B,H,D,N].
__global__ __launch_bounds__(256) void k_qkv(const u16* __restrict__ xh, const u16* __restrict__ xl,
                                             const u16* __restrict__ wh, const u16* __restrict__ wl,
                                             u16* __restrict__ qf, u16* __restrict__ kf,
                                             u16* __restrict__ vt){
    __shared__ u16 Ah[128*64], Al[128*64], Bh[128*64], Bl[128*64];
    const int tid = threadIdx.x, lane = tid & 63, wid = tid >> 6;
    const int lm = lane & 15, lg = lane >> 4;
    const int n0 = blockIdx.x * 128, m0 = blockIdx.y * 128;
    const int t = n0 / 768;                 // 0=q, 1=k, 2=v (128 | 768 boundaries)
    const bool is_v = (t == 2);
    const int wm = (wid >> 1) * 64, wn = (wid & 1) * 64;
    f32x4 acc[4][4];
    const f32x4 z = {0.f, 0.f, 0.f, 0.f};
    #pragma unroll
    for (int i = 0; i < 4; ++i) for (int j = 0; j < 4; ++j) acc[i][j] = z;

    for (int kp = 0; kp < 12; ++kp){
        const int kb = kp * 64;
        #pragma unroll
        for (int c = tid; c < 1024; c += 256){
            int r = c >> 3, cb = c & 7;
            *(bf16x8*)(Ah + r*64 + SW(r,cb)) = *(const bf16x8*)(xh + (size_t)(m0+r)*768 + kb + cb*8);
            if (!is_v)
                *(bf16x8*)(Al + r*64 + SW(r,cb)) = *(const bf16x8*)(xl + (size_t)(m0+r)*768 + kb + cb*8);
        }
        #pragma unroll
        for (int c = tid; c < 1024; c += 256){
            int r = c >> 3, cb = c & 7;
            *(bf16x8*)(Bh + r*64 + SW(r,cb)) = *(const bf16x8*)(wh + (size_t)(n0+r)*768 + kb + cb*8);
            if (!is_v)
                *(bf16x8*)(Bl + r*64 + SW(r,cb)) = *(const bf16x8*)(wl + (size_t)(n0+r)*768 + kb + cb*8);
        }
        __syncthreads();
        #pragma unroll
        for (int ks = 0; ks < 2; ++ks){
            bf16x8 a_h[4], a_l[4], b_h[4], b_l[4];
            #pragma unroll
            for (int mt = 0; mt < 4; ++mt){
                int r = wm + mt*16 + lm, cb = lg + 4*ks;
                a_h[mt] = *(const bf16x8*)(Ah + r*64 + SW(r,cb));
                if (!is_v) a_l[mt] = *(const bf16x8*)(Al + r*64 + SW(r,cb));
            }
            #pragma unroll
            for (int nt = 0; nt < 4; ++nt){
                int r = wn + nt*16 + lm, cb = lg + 4*ks;
                b_h[nt] = *(const bf16x8*)(Bh + r*64 + SW(r,cb));
                if (!is_v) b_l[nt] = *(const bf16x8*)(Bl + r*64 + SW(r,cb));
            }
            #pragma unroll
            for (int mt = 0; mt < 4; ++mt)
            #pragma unroll
            for (int nt = 0; nt < 4; ++nt){
                acc[mt][nt] = __builtin_amdgcn_mfma_f32_16x16x32_bf16(a_h[mt], b_h[nt], acc[mt][nt], 0,0,0);
                if (!is_v){
                    acc[mt][nt] = __builtin_amdgcn_mfma_f32_16x16x32_bf16(a_h[mt], b_l[nt], acc[mt][nt], 0,0,0);
                    acc[mt][nt] = __builtin_amdgcn_mfma_f32_16x16x32_bf16(a_l[mt], b_h[nt], acc[mt][nt], 0,0,0);
                }
            }
        }
        __syncthreads();
    }
    const int nb = n0 % 768;   // offset within the q/k/v third
    #pragma unroll
    for (int mt = 0; mt < 4; ++mt)
    #pragma unroll
    for (int nt = 0; nt < 4; ++nt)
    #pragma unroll
    for (int rr = 0; rr < 4; ++rr){
        int grow = m0 + wm + mt*16 + lg*4 + rr;      // bn
        int dcol = wn + nt*16 + lm;                   // 0..127
        int b = grow >> 11, n = grow & 2047;
        int head = (nb + dcol) >> 6;
        int d    = (nb + dcol) & 63;
        float v = acc[mt][nt][rr];
        if (t == 0)      qf[((size_t)((b*12 + head)*2048 + n))*64 + d] = f16_rne(v * QSCALE);
        else if (t == 1) kf[((size_t)((b*12 + head)*2048 + n))*64 + d] = f16_rne(v);
        else             vt[((size_t)((b*12 + head)*64 + d))*2048 + n] = bf_rne(v);
    }
}

// ---------------- flash attention (swapped QK^T, log2-domain softmax, defer-rescale, T14 prefetch) ----
// grid: x = 32 (q-tiles of 64), y = 48 (b*12+h). 4 waves; wave w owns q-rows [w*16, w*16+16).
__global__ __launch_bounds__(256) void k_attn(const u16* __restrict__ qf, const u16* __restrict__ kf,
                                              const u16* __restrict__ vt, u16* __restrict__ x1h){
    __shared__ u16 Kf[2][64*64], Vs[2][64*64];
    const int tid = threadIdx.x, lane = tid & 63, wid = tid >> 6;
    const int lm = lane & 15, lg = lane >> 4;
    const size_t bh_base = (size_t)blockIdx.y * 2048 * 64;
    const int q0 = blockIdx.x * 64;

    // Q as B-fragment (fp16, pre-scaled by 8*log2e)
    f16x8 qb[2];
    {
        const u16* qp = qf + bh_base + (size_t)(q0 + wid*16 + lm)*64;
        qb[0] = *(const f16x8*)(qp + lg*8);
        qb[1] = *(const f16x8*)(qp + lg*8 + 32);
    }
    f32x4 o_acc[4];
    const f32x4 z = {0.f,0.f,0.f,0.f};
    #pragma unroll
    for (int i = 0; i < 4; ++i) o_acc[i] = z;
    float m_run = -INFINITY, l_run = 0.f;

    const int srcA = ((lg & 1) * 2) * 16 + lm;   // PV A-frag source lanes
    const int srcB = srcA + 16;
    const int hi_sel = lg >> 1;

    // staging geometry: thread owns slots {tid, tid+256} of each 512-chunk tile
    const int r0 = tid >> 3, cb0 = tid & 7;      // r0 in 0..31; second slot r0+32
    const int dK0 = r0*64 + SW(r0,cb0),      dK1 = (r0+32)*64 + SW(r0+32,cb0);
    const u16* kbase = kf + bh_base + r0*64 + cb0*8;          // + kt*4096 (+2048 for slot1)
    const u16* vbase = vt + bh_base + (size_t)r0*2048 + cb0*8; // + kt*64  (+32*2048 for slot1)

    bf16x8 sK0, sK1, sV0, sV1;
    // prologue: tile 0
    sK0 = *(const bf16x8*)(kbase);
    sK1 = *(const bf16x8*)(kbase + 2048);
    sV0 = *(const bf16x8*)(vbase);
    sV1 = *(const bf16x8*)(vbase + 32*2048);
    *(bf16x8*)(Kf[0] + dK0) = sK0;  *(bf16x8*)(Kf[0] + dK1) = sK1;
    *(bf16x8*)(Vs[0] + dK0) = sV0;  *(bf16x8*)(Vs[0] + dK1) = sV1;
    __syncthreads();

    for (int kt = 0; kt < 32; ++kt){
        const int cur = kt & 1;
        // A: issue next tile's global loads (latency hides under compute)
        if (kt < 31){
            const u16* kp = kbase + (kt+1)*4096;
            const u16* vp = vbase + (kt+1)*64;
            sK0 = *(const bf16x8*)(kp);
            sK1 = *(const bf16x8*)(kp + 2048);
            sV0 = *(const bf16x8*)(vp);
            sV1 = *(const bf16x8*)(vp + 32*2048);
        }
        // B: compute tile kt
        const u16* Kc = Kf[cur];
        const u16* Vc = Vs[cur];
        // S^T = K·Q^T in log2 domain: D[row=kk within nt*16][col=q=lm]
        f32x4 st[4];
        #pragma unroll
        for (int i = 0; i < 4; ++i) st[i] = z;
        #pragma unroll
        for (int ks = 0; ks < 2; ++ks){
            #pragma unroll
            for (int nt = 0; nt < 4; ++nt){
                int r = nt*16 + lm, cb = lg + 4*ks;
                f16x8 ka = *(const f16x8*)(Kc + r*64 + SW(r,cb));
                st[nt] = __builtin_amdgcn_mfma_f32_16x16x32_f16(ka, qb[ks], st[nt], 0,0,0);
            }
        }
        // per-lane max of 16 (max3-fusable tree), then cross-lg reduce
        float mx0 = fmaxf(fmaxf(st[0][0], st[0][1]), fmaxf(st[0][2], st[0][3]));
        float mx1 = fmaxf(fmaxf(st[1][0], st[1][1]), fmaxf(st[1][2], st[1][3]));
        float mx2 = fmaxf(fmaxf(st[2][0], st[2][1]), fmaxf(st[2][2], st[2][3]));
        float mx3 = fmaxf(fmaxf(st[3][0], st[3][1]), fmaxf(st[3][2], st[3][3]));
        float lmax = fmaxf(fmaxf(mx0, mx1), fmaxf(mx2, mx3));
        lmax = fmaxf(lmax, __shfl_xor(lmax, 16, 64));
        lmax = fmaxf(lmax, __shfl_xor(lmax, 32, 64));
        // defer-rescale: only pay the rescale when max grew past THR
        if (__any(lmax > m_run + DEFER_THR)){
            float mnew = fmaxf(m_run, lmax);
            float corr = exp2_fast(m_run - mnew);
            m_run = mnew;
            l_run *= corr;
            #pragma unroll
            for (int rr = 0; rr < 4; ++rr){
                float cq = __shfl(corr, (lane & 48) | (lg*4 + rr), 64);
                #pragma unroll
                for (int dt = 0; dt < 4; ++dt) o_acc[dt][rr] *= cq;
            }
        }
        float p[16];
        #pragma unroll
        for (int nt = 0; nt < 4; ++nt)
        #pragma unroll
        for (int rr = 0; rr < 4; ++rr)
            p[nt*4+rr] = exp2_fast(st[nt][rr] - m_run);
        float s01 = (p[0]+p[1]) + (p[2]+p[3]);
        float s23 = (p[4]+p[5]) + (p[6]+p[7]);
        float s45 = (p[8]+p[9]) + (p[10]+p[11]);
        float s67 = (p[12]+p[13]) + (p[14]+p[15]);
        float rsum = (s01+s23) + (s45+s67);
        rsum += __shfl_xor(rsum, 16, 64);
        rsum += __shfl_xor(rsum, 32, 64);
        l_run += rsum;
        // pack P to bf16 pairs via v_cvt_pk_bf16_f32
        unsigned int pk[4][2];
        #pragma unroll
        for (int nt = 0; nt < 4; ++nt)
        #pragma unroll
        for (int h = 0; h < 2; ++h)
            pk[nt][h] = cvtpk_bf16(p[nt*4 + 2*h], p[nt*4 + 2*h + 1]);
        // O += P·V
        #pragma unroll
        for (int ks = 0; ks < 2; ++ks){
            unsigned int w0a = __shfl(pk[ks*2][0],   srcA, 64);
            unsigned int w0b = __shfl(pk[ks*2+1][0], srcA, 64);
            unsigned int w1a = __shfl(pk[ks*2][1],   srcA, 64);
            unsigned int w1b = __shfl(pk[ks*2+1][1], srcA, 64);
            unsigned int w2a = __shfl(pk[ks*2][0],   srcB, 64);
            unsigned int w2b = __shfl(pk[ks*2+1][0], srcB, 64);
            unsigned int w3a = __shfl(pk[ks*2][1],   srcB, 64);
            unsigned int w3b = __shfl(pk[ks*2+1][1], srcB, 64);
            u32x4 wv;
            wv[0] = hi_sel ? w0b : w0a;
            wv[1] = hi_sel ? w1b : w1a;
            wv[2] = hi_sel ? w2b : w2a;
            wv[3] = hi_sel ? w3b : w3a;
            bf16x8 pa = __builtin_bit_cast(bf16x8, wv);
            #pragma unroll
            for (int dt = 0; dt < 4; ++dt){
                int r = dt*16 + lm, cb = lg + 4*ks;
                bf16x8 vb = *(const bf16x8*)(Vc + r*64 + SW(r,cb));
                o_acc[dt] = __builtin_amdgcn_mfma_f32_16x16x32_bf16(pa, vb, o_acc[dt], 0,0,0);
            }
        }
        // C: all waves done reading buf[cur]
        __syncthreads();
        // D: write prefetched tile kt+1 into the other buffer
        if (kt < 31){
            u16* Kn = Kf[cur ^ 1];
            u16* Vn = Vs[cur ^ 1];
            *(bf16x8*)(Kn + dK0) = sK0;  *(bf16x8*)(Kn + dK1) = sK1;
            *(bf16x8*)(Vn + dK0) = sV0;  *(bf16x8*)(Vn + dK1) = sV1;
        }
        // E: writes visible before next iteration's compute
        __syncthreads();
    }
    const int b = blockIdx.y / 12, hh = blockIdx.y % 12;
    #pragma unroll
    for (int rr = 0; rr < 4; ++rr){
        float lr = __shfl(l_run, (lane & 48) | (lg*4 + rr), 64);
        float linv = 1.0f / lr;
        int qrow = q0 + wid*16 + lg*4 + rr;
        #pragma unroll
        for (int dt = 0; dt < 4; ++dt){
            int cc = hh*64 + dt*16 + lm;
            x1h[((size_t)(b*2048 + qrow))*768 + cc] = bf_rne(o_acc[dt][rr] * linv);
        }
    }
}

// ---------------- proj GEMM + bias + residual ----------------
__global__ __launch_bounds__(256) void k_proj(const u16* __restrict__ x1h, const u16* __restrict__ pwh,
                                              const float* __restrict__ pb, const float* __restrict__ xres,
                                              float* __restrict__ out){
    __shared__ u16 Ah[128*64], Bh[64*64];
    const int tid = threadIdx.x, lane = tid & 63, wid = tid >> 6;
    const int lm = lane & 15, lg = lane >> 4;
    const int n0 = blockIdx.x * 64, m0 = blockIdx.y * 128;
    const int wm = (wid >> 1) * 64, wn = (wid & 1) * 32;
    f32x4 acc[4][2];
    const f32x4 z = {0.f,0.f,0.f,0.f};
    #pragma unroll
    for (int i = 0; i < 4; ++i) for (int j = 0; j < 2; ++j) acc[i][j] = z;

    for (int kp = 0; kp < 12; ++kp){
        const int kb = kp * 64;
        #pragma unroll
        for (int c = tid; c < 1024; c += 256){
            int r = c >> 3, cb = c & 7;
            *(bf16x8*)(Ah + r*64 + SW(r,cb)) = *(const bf16x8*)(x1h + (size_t)(m0+r)*768 + kb + cb*8);
        }
        #pragma unroll
        for (int c = tid; c < 512; c += 256){
            int r = c >> 3, cb = c & 7;
            *(bf16x8*)(Bh + r*64 + SW(r,cb)) = *(const bf16x8*)(pwh + (size_t)(n0+r)*768 + kb + cb*8);
        }
        __syncthreads();
        #pragma unroll
        for (int ks = 0; ks < 2; ++ks){
            bf16x8 af[4], bfr[2];
            #pragma unroll
            for (int mt = 0; mt < 4; ++mt){
                int r = wm + mt*16 + lm, cb = lg + 4*ks;
                af[mt] = *(const bf16x8*)(Ah + r*64 + SW(r,cb));
            }
            #pragma unroll
            for (int nt = 0; nt < 2; ++nt){
                int r = wn + nt*16 + lm, cb = lg + 4*ks;
                bfr[nt] = *(const bf16x8*)(Bh + r*64 + SW(r,cb));
            }
            #pragma unroll
            for (int mt = 0; mt < 4; ++mt)
            #pragma unroll
            for (int nt = 0; nt < 2; ++nt)
                acc[mt][nt] = __builtin_amdgcn_mfma_f32_16x16x32_bf16(af[mt], bfr[nt], acc[mt][nt], 0,0,0);
        }
        __syncthreads();
    }
    #pragma unroll
    for (int mt = 0; mt < 4; ++mt)
    #pragma unroll
    for (int nt = 0; nt < 2; ++nt)
    #pragma unroll
    for (int rr = 0; rr < 4; ++rr){
        int grow = m0 + wm + mt*16 + lg*4 + rr;
        int gcol = n0 + wn + nt*16 + lm;
        size_t o = (size_t)grow*768 + gcol;
        out[o] = acc[mt][nt][rr] + pb[gcol] + xres[o];
    }
}

// ---------------- LayerNorm (in-place on out) ----------------
__global__ __launch_bounds__(256) void k_ln(float* __restrict__ out, const float* __restrict__ gamma,
                                            const float* __restrict__ beta){
    const int tid = threadIdx.x, lane = tid & 63, wid = tid >> 6;
    float* p = out + (size_t)blockIdx.x * 768;
    float v[3], s = 0.f, s2 = 0.f;
    #pragma unroll
    for (int j = 0; j < 3; ++j){ v[j] = p[tid + j*256]; s += v[j]; s2 += v[j]*v[j]; }
    #pragma unroll
    for (int mm = 1; mm < 64; mm <<= 1){ s += __shfl_xor(s, mm, 64); s2 += __shfl_xor(s2, mm, 64); }
    __shared__ float red[8];
    if (lane == 0){ red[wid] = s; red[4 + wid] = s2; }
    __syncthreads();
    s  = red[0] + red[1] + red[2] + red[3];
    s2 = red[4] + red[5] + red[6] + red[7];
    const float mu  = s * (1.0f/768.0f);
    const float var = s2 * (1.0f/768.0f) - mu*mu;
    const float inv = rsqrtf(var + 1e-5f);
    #pragma unroll
    for (int j = 0; j < 3; ++j){
        int c = tid + j*256;
        p[c] = (v[j] - mu) * inv * gamma[c] + beta[c];
    }
}

extern "C" void kernel_launch(void* const* d_in, const int* in_sizes, int n_in,
                              void* d_out, int out_size, void* d_ws, size_t ws_size,
                              hipStream_t stream){
    const float* x      = (const float*)d_in[0];
    const float* qkv_w  = (const float*)d_in[1];
    const float* proj_w = (const float*)d_in[2];
    const float* pb     = (const float*)d_in[3];
    const float* gamma  = (const float*)d_in[4];
    const float* beta   = (const float*)d_in[5];
    float* out = (float*)d_out;

    constexpr size_t SZ_X   = 8192ull * 768;
    constexpr size_t SZ_W   = 2304ull * 768;
    constexpr size_t SZ_PW  = 768ull * 768;
    constexpr size_t TOTAL  = 6*SZ_X + 2*SZ_W + 2*SZ_PW;
    if (ws_size < TOTAL * sizeof(u16)) return;

    u16* ws  = (u16*)d_ws;
    u16* xh  = ws;
    u16* xl  = xh  + SZ_X;
    u16* wh  = xl  + SZ_X;
    u16* wl  = wh  + SZ_W;
    u16* pwh = wl  + SZ_W;
    u16* pwl = pwh + SZ_PW;
    u16* qf  = pwl + SZ_PW;
    u16* kf  = qf  + SZ_X;
    u16* vt  = kf  + SZ_X;
    u16* x1h = vt  + SZ_X;

    k_split<<<(SZ_X/4  + 255)/256, 256, 0, stream>>>((const float4*)x,      xh,  xl,  SZ_X/4);
    k_split<<<(SZ_W/4  + 255)/256, 256, 0, stream>>>((const float4*)qkv_w,  wh,  wl,  SZ_W/4);
    k_split<<<(SZ_PW/4 + 255)/256, 256, 0, stream>>>((const float4*)proj_w, pwh, pwl, SZ_PW/4);
    k_qkv <<<dim3(18, 64), 256, 0, stream>>>(xh, xl, wh, wl, qf, kf, vt);
    k_attn<<<dim3(32, 48), 256, 0, stream>>>(qf, kf, vt, x1h);
    k_proj<<<dim3(12, 64), 256, 0, stream>>>(x1h, pwh, pb, x, out);
    k_ln  <<<8192, 256, 0, stream>>>(out, gamma, beta);
}

// Round 5
// 330.342 us; speedup vs baseline: 1.3586x; 1.3586x over previous
//
#include <hip/hip_runtime.h>

typedef unsigned short u16;
typedef __attribute__((ext_vector_type(8))) short bf16x8;
typedef __attribute__((ext_vector_type(8))) _Float16 f16x8;
typedef __attribute__((ext_vector_type(4))) float f32x4;
typedef __attribute__((ext_vector_type(4))) unsigned short us4;
typedef __attribute__((ext_vector_type(4))) unsigned int u32x4;

#define DEV static __device__ __forceinline__

DEV u16 bf_rne(float x){
    unsigned int u = __builtin_bit_cast(unsigned int, x);
    return (u16)((u + 0x7fffu + ((u >> 16) & 1u)) >> 16);
}
DEV u16 f16_rne(float x){ _Float16 h = (_Float16)x; return __builtin_bit_cast(unsigned short, h); }
// packed f32x2 -> bf16x2 (RNE), lo = a, hi = b
DEV unsigned int cvtpk_bf16(float a, float b){
    unsigned int r;
    asm("v_cvt_pk_bf16_f32 %0, %1, %2" : "=v"(r) : "v"(a), "v"(b));
    return r;
}
// 2^x via hardware transcendental (v_exp_f32 computes 2^S0)
DEV float exp2_fast(float x){
    float r;
    asm("v_exp_f32 %0, %1" : "=v"(r) : "v"(x));
    return r;
}
// async global->LDS, 16B per lane; LDS dest must be wave-uniform base + lane*16
DEV void gload_lds16(const void* g, void* l){
    __builtin_amdgcn_global_load_lds((const __attribute__((address_space(1))) unsigned int*)g,
                                     (__attribute__((address_space(3))) unsigned int*)l, 16, 0, 0);
}

#define QSCALE 11.541560327111707f   /* 8 * log2(e): scores come out in log2 domain */
#define DEFER_THR 11.0f              /* allow p up to 2^11 before rescaling (T13) */

// XOR swizzle on 16B column-blocks of a 64-col u16 tile: (r, col-chunk cb) -> r*64 + SW(r,cb)
#define SW(r,cb) ((((cb) ^ ((r)&7)))*8)

// ---------------- fused prep: x -> fp16 hi/lo split; qkv_w -> fp16; proj_w -> bf16 ----------------
// region sizes in float4s: x 1572864 | w 442368 | pw 147456  (all divisible by 256)
__global__ __launch_bounds__(256) void k_prep(const float4* __restrict__ x, const float4* __restrict__ w,
                                              const float4* __restrict__ pw,
                                              u16* __restrict__ xh, u16* __restrict__ xl,
                                              u16* __restrict__ wf, u16* __restrict__ pwh){
    int i = blockIdx.x*256 + threadIdx.x;
    if (i < 1572864){
        float4 v = x[i];
        float vv[4] = {v.x, v.y, v.z, v.w};
        us4 h, l;
        #pragma unroll
        for (int j = 0; j < 4; ++j){
            _Float16 hh = (_Float16)vv[j];
            h[j] = __builtin_bit_cast(unsigned short, hh);
            _Float16 ll = (_Float16)(vv[j] - (float)hh);
            l[j] = __builtin_bit_cast(unsigned short, ll);
        }
        ((us4*)xh)[i] = h;
        ((us4*)xl)[i] = l;
    } else if (i < 1572864 + 442368){
        int j = i - 1572864;
        float4 v = w[j];
        us4 h = { f16_rne(v.x), f16_rne(v.y), f16_rne(v.z), f16_rne(v.w) };
        ((us4*)wf)[j] = h;
    } else {
        int j = i - 2015232;
        float4 v = pw[j];
        us4 h = { bf_rne(v.x), bf_rne(v.y), bf_rne(v.z), bf_rne(v.w) };
        ((us4*)pwh)[j] = h;
    }
}

// ---------------- qkv GEMM (fp16 2-MFMA split; 128x128 tile; global_load_lds staging) ----------------
// C[m][o] = sum_c x[m][c]*W[o][c], M=8192, O=2304, K=768.
// q,k tiles: acc += xh*w + xl*w (x exact to 22 bits, w fp16). v tiles: single MFMA.
// Outputs: q fp16 pre-scaled by 8*log2e; k fp16; v bf16 transposed [B,H,D,N].
__global__ __launch_bounds__(256, 3) void k_qkv(const u16* __restrict__ xh_, const u16* __restrict__ xl_,
                                                const u16* __restrict__ wf_,
                                                u16* __restrict__ qf, u16* __restrict__ kf,
                                                u16* __restrict__ vt){
    __shared__ u16 Ah[128*64], Al[128*64], Bf[128*64];
    const int tid = threadIdx.x, lane = tid & 63, wid = tid >> 6;
    const int lm = lane & 15, lg = lane >> 4;
    const int n0 = blockIdx.x * 128, m0 = blockIdx.y * 128;
    const int t = n0 / 768;                 // 0=q, 1=k, 2=v (6 blocks per third)
    const bool is_v = (t == 2);
    const int wm = (wid >> 1) * 64, wn = (wid & 1) * 64;
    f32x4 acc[4][4];
    const f32x4 z = {0.f, 0.f, 0.f, 0.f};
    #pragma unroll
    for (int i = 0; i < 4; ++i) for (int j = 0; j < 4; ++j) acc[i][j] = z;

    // staging geometry (linear LDS dest, inverse-swizzled global source; rule-21 involution)
    const int c0 = tid;                 // + i*256
    for (int kp = 0; kp < 12; ++kp){
        const int kb = kp * 64;
        #pragma unroll
        for (int i = 0; i < 4; ++i){
            int c = c0 + i*256;
            int r = c >> 3, j = c & 7;
            int sj = (j ^ (r & 7)) * 8;
            gload_lds16(xh_ + (size_t)(m0+r)*768 + kb + sj, Ah + c*8);
            if (!is_v)
                gload_lds16(xl_ + (size_t)(m0+r)*768 + kb + sj, Al + c*8);
            gload_lds16(wf_ + (size_t)(n0+r)*768 + kb + sj, Bf + c*8);
        }
        __syncthreads();   // compiler drains vmcnt before barrier
        #pragma unroll
        for (int ks = 0; ks < 2; ++ks){
            f16x8 a_h[4], a_l[4], b_f[4];
            #pragma unroll
            for (int mt = 0; mt < 4; ++mt){
                int r = wm + mt*16 + lm, cb = lg + 4*ks;
                a_h[mt] = *(const f16x8*)(Ah + r*64 + SW(r,cb));
                if (!is_v) a_l[mt] = *(const f16x8*)(Al + r*64 + SW(r,cb));
            }
            #pragma unroll
            for (int nt = 0; nt < 4; ++nt){
                int r = wn + nt*16 + lm, cb = lg + 4*ks;
                b_f[nt] = *(const f16x8*)(Bf + r*64 + SW(r,cb));
            }
            #pragma unroll
            for (int mt = 0; mt < 4; ++mt)
            #pragma unroll
            for (int nt = 0; nt < 4; ++nt){
                acc[mt][nt] = __builtin_amdgcn_mfma_f32_16x16x32_f16(a_h[mt], b_f[nt], acc[mt][nt], 0,0,0);
                if (!is_v)
                    acc[mt][nt] = __builtin_amdgcn_mfma_f32_16x16x32_f16(a_l[mt], b_f[nt], acc[mt][nt], 0,0,0);
            }
        }
        __syncthreads();
    }
    const int nb = n0 % 768;   // offset within the q/k/v third
    #pragma unroll
    for (int mt = 0; mt < 4; ++mt)
    #pragma unroll
    for (int nt = 0; nt < 4; ++nt)
    #pragma unroll
    for (int rr = 0; rr < 4; ++rr){
        int grow = m0 + wm + mt*16 + lg*4 + rr;      // bn
        int dcol = wn + nt*16 + lm;                   // 0..127
        int b = grow >> 11, n = grow & 2047;
        int head = (nb + dcol) >> 6;
        int d    = (nb + dcol) & 63;
        float v = acc[mt][nt][rr];
        if (t == 0)      qf[((size_t)((b*12 + head)*2048 + n))*64 + d] = f16_rne(v * QSCALE);
        else if (t == 1) kf[((size_t)((b*12 + head)*2048 + n))*64 + d] = f16_rne(v);
        else             vt[((size_t)((b*12 + head)*64 + d))*2048 + n] = bf_rne(v);
    }
}

// ---------------- flash attention (swapped QK^T, log2-domain softmax, defer-rescale, T14 prefetch) ----
// grid: x = 32 (q-tiles of 64), y = 48 (b*12+h). 4 waves; wave w owns q-rows [w*16, w*16+16).
__global__ __launch_bounds__(256) void k_attn(const u16* __restrict__ qf, const u16* __restrict__ kf,
                                              const u16* __restrict__ vt, u16* __restrict__ x1h){
    __shared__ u16 Kf[2][64*64], Vs[2][64*64];
    const int tid = threadIdx.x, lane = tid & 63, wid = tid >> 6;
    const int lm = lane & 15, lg = lane >> 4;
    const size_t bh_base = (size_t)blockIdx.y * 2048 * 64;
    const int q0 = blockIdx.x * 64;

    // Q as B-fragment (fp16, pre-scaled by 8*log2e)
    f16x8 qb[2];
    {
        const u16* qp = qf + bh_base + (size_t)(q0 + wid*16 + lm)*64;
        qb[0] = *(const f16x8*)(qp + lg*8);
        qb[1] = *(const f16x8*)(qp + lg*8 + 32);
    }
    f32x4 o_acc[4];
    const f32x4 z = {0.f,0.f,0.f,0.f};
    #pragma unroll
    for (int i = 0; i < 4; ++i) o_acc[i] = z;
    float m_run = -INFINITY, l_run = 0.f;

    const int srcA = ((lg & 1) * 2) * 16 + lm;   // PV A-frag source lanes
    const int srcB = srcA + 16;
    const int hi_sel = lg >> 1;

    // staging geometry: thread owns slots {tid, tid+256} of each 512-chunk tile
    const int r0 = tid >> 3, cb0 = tid & 7;      // r0 in 0..31; second slot r0+32
    const int dK0 = r0*64 + SW(r0,cb0),      dK1 = (r0+32)*64 + SW(r0+32,cb0);
    const u16* kbase = kf + bh_base + r0*64 + cb0*8;          // + kt*4096 (+2048 for slot1)
    const u16* vbase = vt + bh_base + (size_t)r0*2048 + cb0*8; // + kt*64  (+32*2048 for slot1)

    bf16x8 sK0, sK1, sV0, sV1;
    // prologue: tile 0
    sK0 = *(const bf16x8*)(kbase);
    sK1 = *(const bf16x8*)(kbase + 2048);
    sV0 = *(const bf16x8*)(vbase);
    sV1 = *(const bf16x8*)(vbase + 32*2048);
    *(bf16x8*)(Kf[0] + dK0) = sK0;  *(bf16x8*)(Kf[0] + dK1) = sK1;
    *(bf16x8*)(Vs[0] + dK0) = sV0;  *(bf16x8*)(Vs[0] + dK1) = sV1;
    __syncthreads();

    for (int kt = 0; kt < 32; ++kt){
        const int cur = kt & 1;
        // A: issue next tile's global loads (latency hides under compute)
        if (kt < 31){
            const u16* kp = kbase + (kt+1)*4096;
            const u16* vp = vbase + (kt+1)*64;
            sK0 = *(const bf16x8*)(kp);
            sK1 = *(const bf16x8*)(kp + 2048);
            sV0 = *(const bf16x8*)(vp);
            sV1 = *(const bf16x8*)(vp + 32*2048);
        }
        // B: compute tile kt
        const u16* Kc = Kf[cur];
        const u16* Vc = Vs[cur];
        // S^T = K·Q^T in log2 domain: D[row=kk within nt*16][col=q=lm]
        f32x4 st[4];
        #pragma unroll
        for (int i = 0; i < 4; ++i) st[i] = z;
        #pragma unroll
        for (int ks = 0; ks < 2; ++ks){
            #pragma unroll
            for (int nt = 0; nt < 4; ++nt){
                int r = nt*16 + lm, cb = lg + 4*ks;
                f16x8 ka = *(const f16x8*)(Kc + r*64 + SW(r,cb));
                st[nt] = __builtin_amdgcn_mfma_f32_16x16x32_f16(ka, qb[ks], st[nt], 0,0,0);
            }
        }
        // per-lane max of 16 (max3-fusable tree), then cross-lg reduce
        float mx0 = fmaxf(fmaxf(st[0][0], st[0][1]), fmaxf(st[0][2], st[0][3]));
        float mx1 = fmaxf(fmaxf(st[1][0], st[1][1]), fmaxf(st[1][2], st[1][3]));
        float mx2 = fmaxf(fmaxf(st[2][0], st[2][1]), fmaxf(st[2][2], st[2][3]));
        float mx3 = fmaxf(fmaxf(st[3][0], st[3][1]), fmaxf(st[3][2], st[3][3]));
        float lmax = fmaxf(fmaxf(mx0, mx1), fmaxf(mx2, mx3));
        lmax = fmaxf(lmax, __shfl_xor(lmax, 16, 64));
        lmax = fmaxf(lmax, __shfl_xor(lmax, 32, 64));
        // defer-rescale: only pay the rescale when max grew past THR
        if (__any(lmax > m_run + DEFER_THR)){
            float mnew = fmaxf(m_run, lmax);
            float corr = exp2_fast(m_run - mnew);
            m_run = mnew;
            l_run *= corr;
            #pragma unroll
            for (int rr = 0; rr < 4; ++rr){
                float cq = __shfl(corr, (lane & 48) | (lg*4 + rr), 64);
                #pragma unroll
                for (int dt = 0; dt < 4; ++dt) o_acc[dt][rr] *= cq;
            }
        }
        float p[16];
        #pragma unroll
        for (int nt = 0; nt < 4; ++nt)
        #pragma unroll
        for (int rr = 0; rr < 4; ++rr)
            p[nt*4+rr] = exp2_fast(st[nt][rr] - m_run);
        float s01 = (p[0]+p[1]) + (p[2]+p[3]);
        float s23 = (p[4]+p[5]) + (p[6]+p[7]);
        float s45 = (p[8]+p[9]) + (p[10]+p[11]);
        float s67 = (p[12]+p[13]) + (p[14]+p[15]);
        float rsum = (s01+s23) + (s45+s67);
        rsum += __shfl_xor(rsum, 16, 64);
        rsum += __shfl_xor(rsum, 32, 64);
        l_run += rsum;
        // pack P to bf16 pairs via v_cvt_pk_bf16_f32
        unsigned int pk[4][2];
        #pragma unroll
        for (int nt = 0; nt < 4; ++nt)
        #pragma unroll
        for (int h = 0; h < 2; ++h)
            pk[nt][h] = cvtpk_bf16(p[nt*4 + 2*h], p[nt*4 + 2*h + 1]);
        // O += P·V
        #pragma unroll
        for (int ks = 0; ks < 2; ++ks){
            unsigned int w0a = __shfl(pk[ks*2][0],   srcA, 64);
            unsigned int w0b = __shfl(pk[ks*2+1][0], srcA, 64);
            unsigned int w1a = __shfl(pk[ks*2][1],   srcA, 64);
            unsigned int w1b = __shfl(pk[ks*2+1][1], srcA, 64);
            unsigned int w2a = __shfl(pk[ks*2][0],   srcB, 64);
            unsigned int w2b = __shfl(pk[ks*2+1][0], srcB, 64);
            unsigned int w3a = __shfl(pk[ks*2][1],   srcB, 64);
            unsigned int w3b = __shfl(pk[ks*2+1][1], srcB, 64);
            u32x4 wv;
            wv[0] = hi_sel ? w0b : w0a;
            wv[1] = hi_sel ? w1b : w1a;
            wv[2] = hi_sel ? w2b : w2a;
            wv[3] = hi_sel ? w3b : w3a;
            bf16x8 pa = __builtin_bit_cast(bf16x8, wv);
            #pragma unroll
            for (int dt = 0; dt < 4; ++dt){
                int r = dt*16 + lm, cb = lg + 4*ks;
                bf16x8 vb = *(const bf16x8*)(Vc + r*64 + SW(r,cb));
                o_acc[dt] = __builtin_amdgcn_mfma_f32_16x16x32_bf16(pa, vb, o_acc[dt], 0,0,0);
            }
        }
        // C: all waves done reading buf[cur]
        __syncthreads();
        // D: write prefetched tile kt+1 into the other buffer
        if (kt < 31){
            u16* Kn = Kf[cur ^ 1];
            u16* Vn = Vs[cur ^ 1];
            *(bf16x8*)(Kn + dK0) = sK0;  *(bf16x8*)(Kn + dK1) = sK1;
            *(bf16x8*)(Vn + dK0) = sV0;  *(bf16x8*)(Vn + dK1) = sV1;
        }
        // E: writes visible before next iteration's compute
        __syncthreads();
    }
    const int b = blockIdx.y / 12, hh = blockIdx.y % 12;
    #pragma unroll
    for (int rr = 0; rr < 4; ++rr){
        float lr = __shfl(l_run, (lane & 48) | (lg*4 + rr), 64);
        float linv = 1.0f / lr;
        int qrow = q0 + wid*16 + lg*4 + rr;
        #pragma unroll
        for (int dt = 0; dt < 4; ++dt){
            int cc = hh*64 + dt*16 + lm;
            x1h[((size_t)(b*2048 + qrow))*768 + cc] = bf_rne(o_acc[dt][rr] * linv);
        }
    }
}

// ---------------- proj GEMM + bias + residual ----------------
__global__ __launch_bounds__(256) void k_proj(const u16* __restrict__ x1h, const u16* __restrict__ pwh,
                                              const float* __restrict__ pb, const float* __restrict__ xres,
                                              float* __restrict__ out){
    __shared__ u16 Ah[128*64], Bh[64*64];
    const int tid = threadIdx.x, lane = tid & 63, wid = tid >> 6;
    const int lm = lane & 15, lg = lane >> 4;
    const int n0 = blockIdx.x * 64, m0 = blockIdx.y * 128;
    const int wm = (wid >> 1) * 64, wn = (wid & 1) * 32;
    f32x4 acc[4][2];
    const f32x4 z = {0.f,0.f,0.f,0.f};
    #pragma unroll
    for (int i = 0; i < 4; ++i) for (int j = 0; j < 2; ++j) acc[i][j] = z;

    for (int kp = 0; kp < 12; ++kp){
        const int kb = kp * 64;
        #pragma unroll
        for (int c = tid; c < 1024; c += 256){
            int r = c >> 3, cb = c & 7;
            *(bf16x8*)(Ah + r*64 + SW(r,cb)) = *(const bf16x8*)(x1h + (size_t)(m0+r)*768 + kb + cb*8);
        }
        #pragma unroll
        for (int c = tid; c < 512; c += 256){
            int r = c >> 3, cb = c & 7;
            *(bf16x8*)(Bh + r*64 + SW(r,cb)) = *(const bf16x8*)(pwh + (size_t)(n0+r)*768 + kb + cb*8);
        }
        __syncthreads();
        #pragma unroll
        for (int ks = 0; ks < 2; ++ks){
            bf16x8 af[4], bfr[2];
            #pragma unroll
            for (int mt = 0; mt < 4; ++mt){
                int r = wm + mt*16 + lm, cb = lg + 4*ks;
                af[mt] = *(const bf16x8*)(Ah + r*64 + SW(r,cb));
            }
            #pragma unroll
            for (int nt = 0; nt < 2; ++nt){
                int r = wn + nt*16 + lm, cb = lg + 4*ks;
                bfr[nt] = *(const bf16x8*)(Bh + r*64 + SW(r,cb));
            }
            #pragma unroll
            for (int mt = 0; mt < 4; ++mt)
            #pragma unroll
            for (int nt = 0; nt < 2; ++nt)
                acc[mt][nt] = __builtin_amdgcn_mfma_f32_16x16x32_bf16(af[mt], bfr[nt], acc[mt][nt], 0,0,0);
        }
        __syncthreads();
    }
    #pragma unroll
    for (int mt = 0; mt < 4; ++mt)
    #pragma unroll
    for (int nt = 0; nt < 2; ++nt)
    #pragma unroll
    for (int rr = 0; rr < 4; ++rr){
        int grow = m0 + wm + mt*16 + lg*4 + rr;
        int gcol = n0 + wn + nt*16 + lm;
        size_t o = (size_t)grow*768 + gcol;
        out[o] = acc[mt][nt][rr] + pb[gcol] + xres[o];
    }
}

// ---------------- LayerNorm (in-place on out) ----------------
__global__ __launch_bounds__(256) void k_ln(float* __restrict__ out, const float* __restrict__ gamma,
                                            const float* __restrict__ beta){
    const int tid = threadIdx.x, lane = tid & 63, wid = tid >> 6;
    float* p = out + (size_t)blockIdx.x * 768;
    float v[3], s = 0.f, s2 = 0.f;
    #pragma unroll
    for (int j = 0; j < 3; ++j){ v[j] = p[tid + j*256]; s += v[j]; s2 += v[j]*v[j]; }
    #pragma unroll
    for (int mm = 1; mm < 64; mm <<= 1){ s += __shfl_xor(s, mm, 64); s2 += __shfl_xor(s2, mm, 64); }
    __shared__ float red[8];
    if (lane == 0){ red[wid] = s; red[4 + wid] = s2; }
    __syncthreads();
    s  = red[0] + red[1] + red[2] + red[3];
    s2 = red[4] + red[5] + red[6] + red[7];
    const float mu  = s * (1.0f/768.0f);
    const float var = s2 * (1.0f/768.0f) - mu*mu;
    const float inv = rsqrtf(var + 1e-5f);
    #pragma unroll
    for (int j = 0; j < 3; ++j){
        int c = tid + j*256;
        p[c] = (v[j] - mu) * inv * gamma[c] + beta[c];
    }
}

extern "C" void kernel_launch(void* const* d_in, const int* in_sizes, int n_in,
                              void* d_out, int out_size, void* d_ws, size_t ws_size,
                              hipStream_t stream){
    const float* x      = (const float*)d_in[0];
    const float* qkv_w  = (const float*)d_in[1];
    const float* proj_w = (const float*)d_in[2];
    const float* pb     = (const float*)d_in[3];
    const float* gamma  = (const float*)d_in[4];
    const float* beta   = (const float*)d_in[5];
    float* out = (float*)d_out;

    constexpr size_t SZ_X   = 8192ull * 768;
    constexpr size_t SZ_W   = 2304ull * 768;
    constexpr size_t SZ_PW  = 768ull * 768;
    constexpr size_t TOTAL  = 6*SZ_X + SZ_W + SZ_PW;
    if (ws_size < TOTAL * sizeof(u16)) return;

    u16* ws  = (u16*)d_ws;
    u16* xh  = ws;
    u16* xl  = xh  + SZ_X;
    u16* wf  = xl  + SZ_X;
    u16* pwh = wf  + SZ_W;
    u16* qf  = pwh + SZ_PW;
    u16* kf  = qf  + SZ_X;
    u16* vt  = kf  + SZ_X;
    u16* x1h = vt  + SZ_X;

    // prep grid: (1572864 + 442368 + 147456) float4 / 256 = 8448 blocks
    k_prep<<<8448, 256, 0, stream>>>((const float4*)x, (const float4*)qkv_w, (const float4*)proj_w,
                                     xh, xl, wf, pwh);
    k_qkv <<<dim3(18, 64), 256, 0, stream>>>(xh, xl, wf, qf, kf, vt);
    k_attn<<<dim3(32, 48), 256, 0, stream>>>(qf, kf, vt, x1h);
    k_proj<<<dim3(12, 64), 256, 0, stream>>>(x1h, pwh, pb, x, out);
    k_ln  <<<8192, 256, 0, stream>>>(out, gamma, beta);
}

// Round 6
// 326.237 us; speedup vs baseline: 1.3757x; 1.0126x over previous
//
#include <hip/hip_runtime.h>

typedef unsigned short u16;
typedef __attribute__((ext_vector_type(8))) short bf16x8;
typedef __attribute__((ext_vector_type(8))) _Float16 f16x8;
typedef __attribute__((ext_vector_type(4))) float f32x4;
typedef __attribute__((ext_vector_type(4))) unsigned short us4;
typedef __attribute__((ext_vector_type(4))) unsigned int u32x4;

#define DEV static __device__ __forceinline__

DEV u16 bf_rne(float x){
    unsigned int u = __builtin_bit_cast(unsigned int, x);
    return (u16)((u + 0x7fffu + ((u >> 16) & 1u)) >> 16);
}
DEV u16 f16_rne(float x){ _Float16 h = (_Float16)x; return __builtin_bit_cast(unsigned short, h); }
// packed f32x2 -> bf16x2 (RNE), lo = a, hi = b
DEV unsigned int cvtpk_bf16(float a, float b){
    unsigned int r;
    asm("v_cvt_pk_bf16_f32 %0, %1, %2" : "=v"(r) : "v"(a), "v"(b));
    return r;
}
// 2^x via hardware transcendental (v_exp_f32 computes 2^S0)
DEV float exp2_fast(float x){
    float r;
    asm("v_exp_f32 %0, %1" : "=v"(r) : "v"(x));
    return r;
}
DEV float max3f(float a, float b, float c){
    float r;
    asm("v_max3_f32 %0, %1, %2, %3" : "=v"(r) : "v"(a), "v"(b), "v"(c));
    return r;
}
// async global->LDS, 16B per lane; LDS dest must be wave-uniform base + lane*16
DEV void gload_lds16(const void* g, void* l){
    __builtin_amdgcn_global_load_lds((const __attribute__((address_space(1))) unsigned int*)g,
                                     (__attribute__((address_space(3))) unsigned int*)l, 16, 0, 0);
}

#define QSCALE 11.541560327111707f   /* 8 * log2(e): scores come out in log2 domain */
#define DEFER_THR 11.0f              /* allow p up to 2^11 before rescaling (T13) */

// XOR swizzle on 16B column-blocks of a 64-col u16 tile: (r, col-chunk cb) -> r*64 + SW(r,cb)
#define SW(r,cb) ((((cb) ^ ((r)&7)))*8)

// ---------------- fused prep: x -> fp16; qkv_w -> fp16; proj_w -> bf16 ----------------
// region sizes in float4s: x 1572864 | w 442368 | pw 147456
__global__ __launch_bounds__(256) void k_prep(const float4* __restrict__ x, const float4* __restrict__ w,
                                              const float4* __restrict__ pw,
                                              u16* __restrict__ xf, u16* __restrict__ wf,
                                              u16* __restrict__ pwh){
    int i = blockIdx.x*256 + threadIdx.x;
    if (i < 1572864){
        float4 v = x[i];
        us4 h = { f16_rne(v.x), f16_rne(v.y), f16_rne(v.z), f16_rne(v.w) };
        ((us4*)xf)[i] = h;
    } else if (i < 1572864 + 442368){
        int j = i - 1572864;
        float4 v = w[j];
        us4 h = { f16_rne(v.x), f16_rne(v.y), f16_rne(v.z), f16_rne(v.w) };
        ((us4*)wf)[j] = h;
    } else {
        int j = i - 2015232;
        float4 v = pw[j];
        us4 h = { bf_rne(v.x), bf_rne(v.y), bf_rne(v.z), bf_rne(v.w) };
        ((us4*)pwh)[j] = h;
    }
}

// ---------------- qkv GEMM (fp16 single-MFMA; 128x128 tile; global_load_lds staging) ----------------
// C[m][o] = sum_c x[m][c]*W[o][c], M=8192, O=2304, K=768.
// Outputs: q fp16 pre-scaled by 8*log2e; k fp16; v bf16 transposed [B,H,D,N].
__global__ __launch_bounds__(256, 4) void k_qkv(const u16* __restrict__ xf_, const u16* __restrict__ wf_,
                                                u16* __restrict__ qf, u16* __restrict__ kf,
                                                u16* __restrict__ vt){
    __shared__ u16 Ah[128*64], Bf[128*64];
    const int tid = threadIdx.x, lane = tid & 63, wid = tid >> 6;
    const int lm = lane & 15, lg = lane >> 4;
    const int n0 = blockIdx.x * 128, m0 = blockIdx.y * 128;
    const int t = n0 / 768;                 // 0=q, 1=k, 2=v (6 blocks per third)
    const int wm = (wid >> 1) * 64, wn = (wid & 1) * 64;
    f32x4 acc[4][4];
    const f32x4 z = {0.f, 0.f, 0.f, 0.f};
    #pragma unroll
    for (int i = 0; i < 4; ++i) for (int j = 0; j < 4; ++j) acc[i][j] = z;

    // staging: linear LDS dest (chunk c = tid + i*256), inverse-swizzled global source (rule 21)
    const int rA = tid >> 3, jA = tid & 7;
    const int sj = (jA ^ (rA & 7)) * 8;          // (rA+32k)&7 == rA&7, so sj is i-invariant
    const u16* asrc = xf_ + (size_t)(m0 + rA)*768 + sj;
    const u16* bsrc = wf_ + (size_t)(n0 + rA)*768 + sj;

    for (int kp = 0; kp < 12; ++kp){
        const int kb = kp * 64;
        #pragma unroll
        for (int i = 0; i < 4; ++i){
            gload_lds16(asrc + (size_t)i*(32*768) + kb, Ah + tid*8 + i*2048);
            gload_lds16(bsrc + (size_t)i*(32*768) + kb, Bf + tid*8 + i*2048);
        }
        __syncthreads();   // drains vmcnt before barrier
        #pragma unroll
        for (int ks = 0; ks < 2; ++ks){
            f16x8 a_f[4], b_f[4];
            #pragma unroll
            for (int mt = 0; mt < 4; ++mt){
                int r = wm + mt*16 + lm, cb = lg + 4*ks;
                a_f[mt] = *(const f16x8*)(Ah + r*64 + SW(r,cb));
            }
            #pragma unroll
            for (int nt = 0; nt < 4; ++nt){
                int r = wn + nt*16 + lm, cb = lg + 4*ks;
                b_f[nt] = *(const f16x8*)(Bf + r*64 + SW(r,cb));
            }
            #pragma unroll
            for (int mt = 0; mt < 4; ++mt)
            #pragma unroll
            for (int nt = 0; nt < 4; ++nt)
                acc[mt][nt] = __builtin_amdgcn_mfma_f32_16x16x32_f16(a_f[mt], b_f[nt], acc[mt][nt], 0,0,0);
        }
        __syncthreads();
    }
    const int nb = n0 % 768;   // offset within the q/k/v third
    #pragma unroll
    for (int mt = 0; mt < 4; ++mt)
    #pragma unroll
    for (int nt = 0; nt < 4; ++nt)
    #pragma unroll
    for (int rr = 0; rr < 4; ++rr){
        int grow = m0 + wm + mt*16 + lg*4 + rr;      // bn
        int dcol = wn + nt*16 + lm;                   // 0..127
        int b = grow >> 11, n = grow & 2047;
        int head = (nb + dcol) >> 6;
        int d    = (nb + dcol) & 63;
        float v = acc[mt][nt][rr];
        if (t == 0)      qf[((size_t)((b*12 + head)*2048 + n))*64 + d] = f16_rne(v * QSCALE);
        else if (t == 1) kf[((size_t)((b*12 + head)*2048 + n))*64 + d] = f16_rne(v);
        else             vt[((size_t)((b*12 + head)*64 + d))*2048 + n] = bf_rne(v);
    }
}

// ---------------- flash attention ----------------
// swapped QK^T, log2-domain softmax, defer-rescale, MFMA-ones row sums,
// gload_lds double-buffer with ONE barrier per kv-tile.
// grid: x = 32 (q-tiles of 64), y = 48 (b*12+h). 4 waves; wave w owns q-rows [w*16, w*16+16).
__global__ __launch_bounds__(256) void k_attn(const u16* __restrict__ qf, const u16* __restrict__ kf,
                                              const u16* __restrict__ vt, u16* __restrict__ x1h){
    __shared__ u16 Kf[2][64*64], Vs[2][64*64];
    const int tid = threadIdx.x, lane = tid & 63, wid = tid >> 6;
    const int lm = lane & 15, lg = lane >> 4;
    const size_t bh_base = (size_t)blockIdx.y * 2048 * 64;
    const int q0 = blockIdx.x * 64;

    // Q as B-fragment (fp16, pre-scaled by 8*log2e)
    f16x8 qb[2];
    {
        const u16* qp = qf + bh_base + (size_t)(q0 + wid*16 + lm)*64;
        qb[0] = *(const f16x8*)(qp + lg*8);
        qb[1] = *(const f16x8*)(qp + lg*8 + 32);
    }
    f32x4 o_acc[4], o_sum;
    const f32x4 z = {0.f,0.f,0.f,0.f};
    #pragma unroll
    for (int i = 0; i < 4; ++i) o_acc[i] = z;
    o_sum = z;
    float m_run = -INFINITY;
    bf16x8 ones;
    #pragma unroll
    for (int i = 0; i < 8; ++i) ones[i] = (short)16256;   // bf16 1.0

    const int srcA = ((lg & 1) * 2) * 16 + lm;   // PV A-frag source lanes
    const int srcB = srcA + 16;
    const int hi_sel = lg >> 1;

    // staging: linear LDS dest chunk = tid (+256), inverse-swizzled global source
    const int rA = tid >> 3, jA = tid & 7;
    const int sj = (jA ^ (rA & 7)) * 8;
    const u16* ksrc = kf + bh_base + rA*64 + sj;            // + kt*4096; slot2 +2048 (rows +32)
    const u16* vsrc = vt + bh_base + (size_t)rA*2048 + sj;  // + kt*64;  slot2 +32*2048

    #define STAGE(kt_, b_) do { \
        const u16* kp_ = ksrc + (size_t)(kt_)*4096; \
        const u16* vp_ = vsrc + (size_t)(kt_)*64; \
        u16* lk_ = Kf[b_] + tid*8; \
        u16* lv_ = Vs[b_] + tid*8; \
        gload_lds16(kp_,            lk_); \
        gload_lds16(kp_ + 2048,     lk_ + 2048); \
        gload_lds16(vp_,            lv_); \
        gload_lds16(vp_ + 32*2048,  lv_ + 2048); \
    } while(0)

    STAGE(0, 0);
    __syncthreads();

    for (int kt = 0; kt < 32; ++kt){
        const int cur = kt & 1;
        if (kt < 31) STAGE(kt + 1, cur ^ 1);    // async into the other buffer
        const u16* Kc = Kf[cur];
        const u16* Vc = Vs[cur];
        // S^T = K·Q^T in log2 domain: st[nt][rr] = S^T[kk = nt*16+lg*4+rr][q = lm]
        f32x4 st[4];
        #pragma unroll
        for (int i = 0; i < 4; ++i) st[i] = z;
        #pragma unroll
        for (int ks = 0; ks < 2; ++ks){
            #pragma unroll
            for (int nt = 0; nt < 4; ++nt){
                int r = nt*16 + lm, cb = lg + 4*ks;
                f16x8 ka = *(const f16x8*)(Kc + r*64 + SW(r,cb));
                st[nt] = __builtin_amdgcn_mfma_f32_16x16x32_f16(ka, qb[ks], st[nt], 0,0,0);
            }
        }
        // per-lane max of 16 via v_max3, then cross-lg reduce
        float g0 = max3f(st[0][0], st[0][1], st[0][2]);
        float g1 = max3f(st[0][3], st[1][0], st[1][1]);
        float g2 = max3f(st[1][2], st[1][3], st[2][0]);
        float g3 = max3f(st[2][1], st[2][2], st[2][3]);
        float g4 = max3f(st[3][0], st[3][1], st[3][2]);
        float lmax = fmaxf(max3f(g0, g1, g2), max3f(g3, g4, st[3][3]));
        lmax = fmaxf(lmax, __shfl_xor(lmax, 16, 64));
        lmax = fmaxf(lmax, __shfl_xor(lmax, 32, 64));
        // defer-rescale: only pay when max grew past THR
        if (__any(lmax > m_run + DEFER_THR)){
            float mnew = fmaxf(m_run, lmax);
            float corr = exp2_fast(m_run - mnew);
            m_run = mnew;
            #pragma unroll
            for (int rr = 0; rr < 4; ++rr){
                float cq = __shfl(corr, (lane & 48) | (lg*4 + rr), 64);
                o_sum[rr] *= cq;
                #pragma unroll
                for (int dt = 0; dt < 4; ++dt) o_acc[dt][rr] *= cq;
            }
        }
        float p[16];
        #pragma unroll
        for (int nt = 0; nt < 4; ++nt)
        #pragma unroll
        for (int rr = 0; rr < 4; ++rr)
            p[nt*4+rr] = exp2_fast(st[nt][rr] - m_run);
        // pack P to bf16 pairs
        unsigned int pk[4][2];
        #pragma unroll
        for (int nt = 0; nt < 4; ++nt)
        #pragma unroll
        for (int h = 0; h < 2; ++h)
            pk[nt][h] = cvtpk_bf16(p[nt*4 + 2*h], p[nt*4 + 2*h + 1]);
        // O += P·V ; row-sums via MFMA with ones-B (l = P·1)
        #pragma unroll
        for (int ks = 0; ks < 2; ++ks){
            unsigned int w0a = __shfl(pk[ks*2][0],   srcA, 64);
            unsigned int w0b = __shfl(pk[ks*2+1][0], srcA, 64);
            unsigned int w1a = __shfl(pk[ks*2][1],   srcA, 64);
            unsigned int w1b = __shfl(pk[ks*2+1][1], srcA, 64);
            unsigned int w2a = __shfl(pk[ks*2][0],   srcB, 64);
            unsigned int w2b = __shfl(pk[ks*2+1][0], srcB, 64);
            unsigned int w3a = __shfl(pk[ks*2][1],   srcB, 64);
            unsigned int w3b = __shfl(pk[ks*2+1][1], srcB, 64);
            u32x4 wv;
            wv[0] = hi_sel ? w0b : w0a;
            wv[1] = hi_sel ? w1b : w1a;
            wv[2] = hi_sel ? w2b : w2a;
            wv[3] = hi_sel ? w3b : w3a;
            bf16x8 pa = __builtin_bit_cast(bf16x8, wv);
            o_sum = __builtin_amdgcn_mfma_f32_16x16x32_bf16(pa, ones, o_sum, 0,0,0);
            #pragma unroll
            for (int dt = 0; dt < 4; ++dt){
                int r = dt*16 + lm, cb = lg + 4*ks;
                bf16x8 vb = *(const bf16x8*)(Vc + r*64 + SW(r,cb));
                o_acc[dt] = __builtin_amdgcn_mfma_f32_16x16x32_bf16(pa, vb, o_acc[dt], 0,0,0);
            }
        }
        // single barrier: all waves done reading buf[cur]; drains the async
        // gload_lds for tile kt+1 so buf[cur^1] is ready for the next iter.
        __syncthreads();
    }
    #undef STAGE
    const int b = blockIdx.y / 12, hh = blockIdx.y % 12;
    #pragma unroll
    for (int rr = 0; rr < 4; ++rr){
        float linv = 1.0f / o_sum[rr];     // row-sum lives in-lane (D layout row = lg*4+rr)
        int qrow = q0 + wid*16 + lg*4 + rr;
        #pragma unroll
        for (int dt = 0; dt < 4; ++dt){
            int cc = hh*64 + dt*16 + lm;
            x1h[((size_t)(b*2048 + qrow))*768 + cc] = bf_rne(o_acc[dt][rr] * linv);
        }
    }
}

// ---------------- proj GEMM + bias + residual ----------------
__global__ __launch_bounds__(256) void k_proj(const u16* __restrict__ x1h, const u16* __restrict__ pwh,
                                              const float* __restrict__ pb, const float* __restrict__ xres,
                                              float* __restrict__ out){
    __shared__ u16 Ah[128*64], Bh[64*64];
    const int tid = threadIdx.x, lane = tid & 63, wid = tid >> 6;
    const int lm = lane & 15, lg = lane >> 4;
    const int n0 = blockIdx.x * 64, m0 = blockIdx.y * 128;
    const int wm = (wid >> 1) * 64, wn = (wid & 1) * 32;
    f32x4 acc[4][2];
    const f32x4 z = {0.f,0.f,0.f,0.f};
    #pragma unroll
    for (int i = 0; i < 4; ++i) for (int j = 0; j < 2; ++j) acc[i][j] = z;

    for (int kp = 0; kp < 12; ++kp){
        const int kb = kp * 64;
        #pragma unroll
        for (int c = tid; c < 1024; c += 256){
            int r = c >> 3, cb = c & 7;
            *(bf16x8*)(Ah + r*64 + SW(r,cb)) = *(const bf16x8*)(x1h + (size_t)(m0+r)*768 + kb + cb*8);
        }
        #pragma unroll
        for (int c = tid; c < 512; c += 256){
            int r = c >> 3, cb = c & 7;
            *(bf16x8*)(Bh + r*64 + SW(r,cb)) = *(const bf16x8*)(pwh + (size_t)(n0+r)*768 + kb + cb*8);
        }
        __syncthreads();
        #pragma unroll
        for (int ks = 0; ks < 2; ++ks){
            bf16x8 af[4], bfr[2];
            #pragma unroll
            for (int mt = 0; mt < 4; ++mt){
                int r = wm + mt*16 + lm, cb = lg + 4*ks;
                af[mt] = *(const bf16x8*)(Ah + r*64 + SW(r,cb));
            }
            #pragma unroll
            for (int nt = 0; nt < 2; ++nt){
                int r = wn + nt*16 + lm, cb = lg + 4*ks;
                bfr[nt] = *(const bf16x8*)(Bh + r*64 + SW(r,cb));
            }
            #pragma unroll
            for (int mt = 0; mt < 4; ++mt)
            #pragma unroll
            for (int nt = 0; nt < 2; ++nt)
                acc[mt][nt] = __builtin_amdgcn_mfma_f32_16x16x32_bf16(af[mt], bfr[nt], acc[mt][nt], 0,0,0);
        }
        __syncthreads();
    }
    #pragma unroll
    for (int mt = 0; mt < 4; ++mt)
    #pragma unroll
    for (int nt = 0; nt < 2; ++nt)
    #pragma unroll
    for (int rr = 0; rr < 4; ++rr){
        int grow = m0 + wm + mt*16 + lg*4 + rr;
        int gcol = n0 + wn + nt*16 + lm;
        size_t o = (size_t)grow*768 + gcol;
        out[o] = acc[mt][nt][rr] + pb[gcol] + xres[o];
    }
}

// ---------------- LayerNorm (in-place on out) ----------------
__global__ __launch_bounds__(256) void k_ln(float* __restrict__ out, const float* __restrict__ gamma,
                                            const float* __restrict__ beta){
    const int tid = threadIdx.x, lane = tid & 63, wid = tid >> 6;
    float* p = out + (size_t)blockIdx.x * 768;
    float v[3], s = 0.f, s2 = 0.f;
    #pragma unroll
    for (int j = 0; j < 3; ++j){ v[j] = p[tid + j*256]; s += v[j]; s2 += v[j]*v[j]; }
    #pragma unroll
    for (int mm = 1; mm < 64; mm <<= 1){ s += __shfl_xor(s, mm, 64); s2 += __shfl_xor(s2, mm, 64); }
    __shared__ float red[8];
    if (lane == 0){ red[wid] = s; red[4 + wid] = s2; }
    __syncthreads();
    s  = red[0] + red[1] + red[2] + red[3];
    s2 = red[4] + red[5] + red[6] + red[7];
    const float mu  = s * (1.0f/768.0f);
    const float var = s2 * (1.0f/768.0f) - mu*mu;
    const float inv = rsqrtf(var + 1e-5f);
    #pragma unroll
    for (int j = 0; j < 3; ++j){
        int c = tid + j*256;
        p[c] = (v[j] - mu) * inv * gamma[c] + beta[c];
    }
}

extern "C" void kernel_launch(void* const* d_in, const int* in_sizes, int n_in,
                              void* d_out, int out_size, void* d_ws, size_t ws_size,
                              hipStream_t stream){
    const float* x      = (const float*)d_in[0];
    const float* qkv_w  = (const float*)d_in[1];
    const float* proj_w = (const float*)d_in[2];
    const float* pb     = (const float*)d_in[3];
    const float* gamma  = (const float*)d_in[4];
    const float* beta   = (const float*)d_in[5];
    float* out = (float*)d_out;

    constexpr size_t SZ_X   = 8192ull * 768;
    constexpr size_t SZ_W   = 2304ull * 768;
    constexpr size_t SZ_PW  = 768ull * 768;
    constexpr size_t TOTAL  = 5*SZ_X + SZ_W + SZ_PW;
    if (ws_size < TOTAL * sizeof(u16)) return;

    u16* ws  = (u16*)d_ws;
    u16* xf  = ws;
    u16* wf  = xf  + SZ_X;
    u16* pwh = wf  + SZ_W;
    u16* qf  = pwh + SZ_PW;
    u16* kf  = qf  + SZ_X;
    u16* vt  = kf  + SZ_X;
    u16* x1h = vt  + SZ_X;

    // prep grid: (1572864 + 442368 + 147456) float4 / 256 = 8448 blocks
    k_prep<<<8448, 256, 0, stream>>>((const float4*)x, (const float4*)qkv_w, (const float4*)proj_w,
                                     xf, wf, pwh);
    k_qkv <<<dim3(18, 64), 256, 0, stream>>>(xf, wf, qf, kf, vt);
    k_attn<<<dim3(32, 48), 256, 0, stream>>>(qf, kf, vt, x1h);
    k_proj<<<dim3(12, 64), 256, 0, stream>>>(x1h, pwh, pb, x, out);
    k_ln  <<<8192, 256, 0, stream>>>(out, gamma, beta);
}

// Round 9
// 300.139 us; speedup vs baseline: 1.4953x; 1.0870x over previous
//
#include <hip/hip_runtime.h>

typedef unsigned short u16;
typedef __attribute__((ext_vector_type(8))) short bf16x8;
typedef __attribute__((ext_vector_type(8))) _Float16 f16x8;
typedef __attribute__((ext_vector_type(4))) float f32x4;
typedef __attribute__((ext_vector_type(4))) unsigned short us4;
typedef __attribute__((ext_vector_type(4))) unsigned int u32x4;

#define DEV static __device__ __forceinline__

DEV u16 bf_rne(float x){
    unsigned int u = __builtin_bit_cast(unsigned int, x);
    return (u16)((u + 0x7fffu + ((u >> 16) & 1u)) >> 16);
}
DEV u16 f16_rne(float x){ _Float16 h = (_Float16)x; return __builtin_bit_cast(unsigned short, h); }
// packed f32x2 -> bf16x2 (RNE), lo = a, hi = b
DEV unsigned int cvtpk_bf16(float a, float b){
    unsigned int r;
    asm("v_cvt_pk_bf16_f32 %0, %1, %2" : "=v"(r) : "v"(a), "v"(b));
    return r;
}
// 2^x via hardware transcendental (v_exp_f32 computes 2^S0)
DEV float exp2_fast(float x){
    float r;
    asm("v_exp_f32 %0, %1" : "=v"(r) : "v"(x));
    return r;
}
DEV float max3f(float a, float b, float c){
    float r;
    asm("v_max3_f32 %0, %1, %2, %3" : "=v"(r) : "v"(a), "v"(b), "v"(c));
    return r;
}
// async global->LDS, 16B per lane; LDS dest must be wave-uniform base + lane*16
DEV void gload_lds16(const void* g, void* l){
    __builtin_amdgcn_global_load_lds((const __attribute__((address_space(1))) unsigned int*)g,
                                     (__attribute__((address_space(3))) unsigned int*)l, 16, 0, 0);
}

#define QSCALE 11.541560327111707f   /* 8 * log2(e): scores come out in log2 domain */
#define DEFER_THR 11.0f              /* allow p up to 2^11 before rescaling (T13) */

// XOR swizzle on 16B column-blocks of a 64-col u16 tile: (r, col-chunk cb) -> r*64 + SW(r,cb)
#define SW(r,cb) ((((cb) ^ ((r)&7)))*8)

// ---------------- fused prep: x -> fp16; qkv_w -> fp16; proj_w -> bf16 ----------------
// region sizes in float4s: x 1572864 | w 442368 | pw 147456
__global__ __launch_bounds__(256) void k_prep(const float4* __restrict__ x, const float4* __restrict__ w,
                                              const float4* __restrict__ pw,
                                              u16* __restrict__ xf, u16* __restrict__ wf,
                                              u16* __restrict__ pwh){
    int i = blockIdx.x*256 + threadIdx.x;
    if (i < 1572864){
        float4 v = x[i];
        us4 h = { f16_rne(v.x), f16_rne(v.y), f16_rne(v.z), f16_rne(v.w) };
        ((us4*)xf)[i] = h;
    } else if (i < 1572864 + 442368){
        int j = i - 1572864;
        float4 v = w[j];
        us4 h = { f16_rne(v.x), f16_rne(v.y), f16_rne(v.z), f16_rne(v.w) };
        ((us4*)wf)[j] = h;
    } else {
        int j = i - 2015232;
        float4 v = pw[j];
        us4 h = { bf_rne(v.x), bf_rne(v.y), bf_rne(v.z), bf_rne(v.w) };
        ((us4*)pwh)[j] = h;
    }
}

// ---------------- qkv GEMM (fp16 single-MFMA; 128x128 tile; global_load_lds staging) ----------------
// V epilogue routed through LDS transpose for coalesced 16B stores (q/k paths unchanged).
__global__ __launch_bounds__(256, 4) void k_qkv(const u16* __restrict__ xf_, const u16* __restrict__ wf_,
                                                u16* __restrict__ qf, u16* __restrict__ kf,
                                                u16* __restrict__ vt){
    __shared__ u16 Ah[128*64], Bf[128*64];
    const int tid = threadIdx.x, lane = tid & 63, wid = tid >> 6;
    const int lm = lane & 15, lg = lane >> 4;
    const int n0 = blockIdx.x * 128, m0 = blockIdx.y * 128;
    const int t = n0 / 768;                 // 0=q, 1=k, 2=v
    const int wm = (wid >> 1) * 64, wn = (wid & 1) * 64;
    f32x4 acc[4][4];
    const f32x4 z = {0.f, 0.f, 0.f, 0.f};
    #pragma unroll
    for (int i = 0; i < 4; ++i) for (int j = 0; j < 4; ++j) acc[i][j] = z;

    const int rA = tid >> 3, jA = tid & 7;
    const int sj = (jA ^ (rA & 7)) * 8;
    const u16* asrc = xf_ + (size_t)(m0 + rA)*768 + sj;
    const u16* bsrc = wf_ + (size_t)(n0 + rA)*768 + sj;

    for (int kp = 0; kp < 12; ++kp){
        const int kb = kp * 64;
        #pragma unroll
        for (int i = 0; i < 4; ++i){
            gload_lds16(asrc + (size_t)i*(32*768) + kb, Ah + tid*8 + i*2048);
            gload_lds16(bsrc + (size_t)i*(32*768) + kb, Bf + tid*8 + i*2048);
        }
        __syncthreads();
        #pragma unroll
        for (int ks = 0; ks < 2; ++ks){
            f16x8 a_f[4], b_f[4];
            #pragma unroll
            for (int mt = 0; mt < 4; ++mt){
                int r = wm + mt*16 + lm, cb = lg + 4*ks;
                a_f[mt] = *(const f16x8*)(Ah + r*64 + SW(r,cb));
            }
            #pragma unroll
            for (int nt = 0; nt < 4; ++nt){
                int r = wn + nt*16 + lm, cb = lg + 4*ks;
                b_f[nt] = *(const f16x8*)(Bf + r*64 + SW(r,cb));
            }
            #pragma unroll
            for (int mt = 0; mt < 4; ++mt)
            #pragma unroll
            for (int nt = 0; nt < 4; ++nt)
                acc[mt][nt] = __builtin_amdgcn_mfma_f32_16x16x32_f16(a_f[mt], b_f[nt], acc[mt][nt], 0,0,0);
        }
        __syncthreads();
    }
    const int nb = n0 % 768;
    if (t < 2){
        #pragma unroll
        for (int mt = 0; mt < 4; ++mt)
        #pragma unroll
        for (int nt = 0; nt < 4; ++nt)
        #pragma unroll
        for (int rr = 0; rr < 4; ++rr){
            int grow = m0 + wm + mt*16 + lg*4 + rr;
            int dcol = wn + nt*16 + lm;
            int b = grow >> 11, n = grow & 2047;
            int head = (nb + dcol) >> 6;
            int d    = (nb + dcol) & 63;
            float v = acc[mt][nt][rr];
            if (t == 0) qf[((size_t)((b*12 + head)*2048 + n))*64 + d] = f16_rne(v * QSCALE);
            else        kf[((size_t)((b*12 + head)*2048 + n))*64 + d] = f16_rne(v);
        }
    } else {
        // V: transpose through LDS (Ah free after final barrier), then coalesced stores along n.
        const int b = m0 >> 11;            // m0 is 128-aligned: block never crosses a batch boundary
        const int nbase = m0 & 2047;
        u16* T = Ah;                        // [64][128] = 8192 u16
        #pragma unroll
        for (int h = 0; h < 2; ++h){
            __syncthreads();                // block-uniform (t depends only on blockIdx.x)
            if ((wid & 1) == h){            // waves owning dcol half h (wn == h*64)
                #pragma unroll
                for (int mt = 0; mt < 4; ++mt)
                #pragma unroll
                for (int nt = 0; nt < 4; ++nt)
                #pragma unroll
                for (int rr = 0; rr < 4; ++rr){
                    int dl = nt*16 + lm;               // 0..63 within half
                    int ml = wm + mt*16 + lg*4 + rr;   // 0..127
                    T[dl*128 + ml] = bf_rne(acc[mt][nt][rr]);
                }
            }
            __syncthreads();
            {
                int r  = tid >> 2;           // 0..63
                int c0 = (tid & 3) * 32;     // 0,32,64,96
                int dcol = h*64 + r;
                int head = (nb + dcol) >> 6;
                int d    = (nb + dcol) & 63;
                u16* dst = vt + ((size_t)((b*12 + head)*64 + d))*2048 + nbase + c0;
                #pragma unroll
                for (int j = 0; j < 4; ++j)
                    *(bf16x8*)(dst + j*8) = *(const bf16x8*)(T + r*128 + c0 + j*8);
            }
        }
    }
}

// ---------------- flash attention (R6-green, byte-identical) ----------------
// 4 waves, QBLK=64; swapped QK^T, log2-domain softmax, defer-rescale, MFMA-ones row sums,
// gload_lds double-buffer with ONE barrier per kv-tile.
// grid: x = 32 (q-tiles of 64), y = 48 (b*12+h). wave w owns q-rows [w*16, w*16+16).
__global__ __launch_bounds__(256) void k_attn(const u16* __restrict__ qf, const u16* __restrict__ kf,
                                              const u16* __restrict__ vt, u16* __restrict__ x1h){
    __shared__ u16 Kf[2][64*64], Vs[2][64*64];
    const int tid = threadIdx.x, lane = tid & 63, wid = tid >> 6;
    const int lm = lane & 15, lg = lane >> 4;
    const size_t bh_base = (size_t)blockIdx.y * 2048 * 64;
    const int q0 = blockIdx.x * 64;

    // Q as B-fragment (fp16, pre-scaled by 8*log2e)
    f16x8 qb[2];
    {
        const u16* qp = qf + bh_base + (size_t)(q0 + wid*16 + lm)*64;
        qb[0] = *(const f16x8*)(qp + lg*8);
        qb[1] = *(const f16x8*)(qp + lg*8 + 32);
    }
    f32x4 o_acc[4], o_sum;
    const f32x4 z = {0.f,0.f,0.f,0.f};
    #pragma unroll
    for (int i = 0; i < 4; ++i) o_acc[i] = z;
    o_sum = z;
    float m_run = -INFINITY;
    bf16x8 ones;
    #pragma unroll
    for (int i = 0; i < 8; ++i) ones[i] = (short)16256;   // bf16 1.0

    const int srcA = ((lg & 1) * 2) * 16 + lm;   // PV A-frag source lanes
    const int srcB = srcA + 16;
    const int hi_sel = lg >> 1;

    // staging: 256 threads, 2 K-chunks + 2 V-chunks each; linear LDS dest, inverse-swizzled source
    const int rA = tid >> 3, jA = tid & 7;       // rA 0..31
    const int sj = (jA ^ (rA & 7)) * 8;
    const u16* ksrc = kf + bh_base + rA*64 + sj;            // + kt*4096
    const u16* vsrc = vt + bh_base + (size_t)rA*2048 + sj;  // + kt*64

    #define STAGE(kt_, b_) do { \
        const u16* kp_ = ksrc + (size_t)(kt_)*4096; \
        const u16* vp_ = vsrc + (size_t)(kt_)*64; \
        u16* lk_ = Kf[b_] + tid*8; \
        u16* lv_ = Vs[b_] + tid*8; \
        gload_lds16(kp_,            lk_); \
        gload_lds16(kp_ + 2048,     lk_ + 2048); \
        gload_lds16(vp_,            lv_); \
        gload_lds16(vp_ + 32*2048,  lv_ + 2048); \
    } while(0)

    STAGE(0, 0);
    __syncthreads();

    for (int kt = 0; kt < 32; ++kt){
        const int cur = kt & 1;
        if (kt < 31) STAGE(kt + 1, cur ^ 1);    // async into the other buffer
        const u16* Kc = Kf[cur];
        const u16* Vc = Vs[cur];
        // S^T = K·Q^T in log2 domain: st[nt][rr] = S^T[kk = nt*16+lg*4+rr][q = lm]
        f32x4 st[4];
        #pragma unroll
        for (int i = 0; i < 4; ++i) st[i] = z;
        #pragma unroll
        for (int ks = 0; ks < 2; ++ks){
            #pragma unroll
            for (int nt = 0; nt < 4; ++nt){
                int r = nt*16 + lm, cb = lg + 4*ks;
                f16x8 ka = *(const f16x8*)(Kc + r*64 + SW(r,cb));
                st[nt] = __builtin_amdgcn_mfma_f32_16x16x32_f16(ka, qb[ks], st[nt], 0,0,0);
            }
        }
        // per-lane max of 16 via v_max3, then cross-lg reduce
        float g0 = max3f(st[0][0], st[0][1], st[0][2]);
        float g1 = max3f(st[0][3], st[1][0], st[1][1]);
        float g2 = max3f(st[1][2], st[1][3], st[2][0]);
        float g3 = max3f(st[2][1], st[2][2], st[2][3]);
        float g4 = max3f(st[3][0], st[3][1], st[3][2]);
        float lmax = fmaxf(max3f(g0, g1, g2), max3f(g3, g4, st[3][3]));
        lmax = fmaxf(lmax, __shfl_xor(lmax, 16, 64));
        lmax = fmaxf(lmax, __shfl_xor(lmax, 32, 64));
        // defer-rescale: only pay when max grew past THR
        if (__any(lmax > m_run + DEFER_THR)){
            float mnew = fmaxf(m_run, lmax);
            float corr = exp2_fast(m_run - mnew);
            m_run = mnew;
            #pragma unroll
            for (int rr = 0; rr < 4; ++rr){
                float cq = __shfl(corr, (lane & 48) | (lg*4 + rr), 64);
                o_sum[rr] *= cq;
                #pragma unroll
                for (int dt = 0; dt < 4; ++dt) o_acc[dt][rr] *= cq;
            }
        }
        float p[16];
        #pragma unroll
        for (int nt = 0; nt < 4; ++nt)
        #pragma unroll
        for (int rr = 0; rr < 4; ++rr)
            p[nt*4+rr] = exp2_fast(st[nt][rr] - m_run);
        // pack P to bf16 pairs
        unsigned int pk[4][2];
        #pragma unroll
        for (int nt = 0; nt < 4; ++nt)
        #pragma unroll
        for (int h = 0; h < 2; ++h)
            pk[nt][h] = cvtpk_bf16(p[nt*4 + 2*h], p[nt*4 + 2*h + 1]);
        // O += P·V ; row-sums via MFMA with ones-B (l = P·1)
        #pragma unroll
        for (int ks = 0; ks < 2; ++ks){
            unsigned int w0a = __shfl(pk[ks*2][0],   srcA, 64);
            unsigned int w0b = __shfl(pk[ks*2+1][0], srcA, 64);
            unsigned int w1a = __shfl(pk[ks*2][1],   srcA, 64);
            unsigned int w1b = __shfl(pk[ks*2+1][1], srcA, 64);
            unsigned int w2a = __shfl(pk[ks*2][0],   srcB, 64);
            unsigned int w2b = __shfl(pk[ks*2+1][0], srcB, 64);
            unsigned int w3a = __shfl(pk[ks*2][1],   srcB, 64);
            unsigned int w3b = __shfl(pk[ks*2+1][1], srcB, 64);
            u32x4 wv;
            wv[0] = hi_sel ? w0b : w0a;
            wv[1] = hi_sel ? w1b : w1a;
            wv[2] = hi_sel ? w2b : w2a;
            wv[3] = hi_sel ? w3b : w3a;
            bf16x8 pa = __builtin_bit_cast(bf16x8, wv);
            o_sum = __builtin_amdgcn_mfma_f32_16x16x32_bf16(pa, ones, o_sum, 0,0,0);
            #pragma unroll
            for (int dt = 0; dt < 4; ++dt){
                int r = dt*16 + lm, cb = lg + 4*ks;
                bf16x8 vb = *(const bf16x8*)(Vc + r*64 + SW(r,cb));
                o_acc[dt] = __builtin_amdgcn_mfma_f32_16x16x32_bf16(pa, vb, o_acc[dt], 0,0,0);
            }
        }
        // single barrier: waves done reading buf[cur]; drains async gload_lds for kt+1
        __syncthreads();
    }
    #undef STAGE
    const int b = blockIdx.y / 12, hh = blockIdx.y % 12;
    #pragma unroll
    for (int rr = 0; rr < 4; ++rr){
        float linv = 1.0f / o_sum[rr];
        int qrow = q0 + wid*16 + lg*4 + rr;
        #pragma unroll
        for (int dt = 0; dt < 4; ++dt){
            int cc = hh*64 + dt*16 + lm;
            x1h[((size_t)(b*2048 + qrow))*768 + cc] = bf_rne(o_acc[dt][rr] * linv);
        }
    }
}

// ---------------- proj GEMM + bias + residual (ds_write staging, known good) ----------------
__global__ __launch_bounds__(256) void k_proj(const u16* __restrict__ x1h, const u16* __restrict__ pwh,
                                              const float* __restrict__ pb, const float* __restrict__ xres,
                                              float* __restrict__ out){
    __shared__ u16 Ah[128*64], Bh[64*64];
    const int tid = threadIdx.x, lane = tid & 63, wid = tid >> 6;
    const int lm = lane & 15, lg = lane >> 4;
    const int n0 = blockIdx.x * 64, m0 = blockIdx.y * 128;
    const int wm = (wid >> 1) * 64, wn = (wid & 1) * 32;
    f32x4 acc[4][2];
    const f32x4 z = {0.f,0.f,0.f,0.f};
    #pragma unroll
    for (int i = 0; i < 4; ++i) for (int j = 0; j < 2; ++j) acc[i][j] = z;

    for (int kp = 0; kp < 12; ++kp){
        const int kb = kp * 64;
        #pragma unroll
        for (int c = tid; c < 1024; c += 256){
            int r = c >> 3, cb = c & 7;
            *(bf16x8*)(Ah + r*64 + SW(r,cb)) = *(const bf16x8*)(x1h + (size_t)(m0+r)*768 + kb + cb*8);
        }
        #pragma unroll
        for (int c = tid; c < 512; c += 256){
            int r = c >> 3, cb = c & 7;
            *(bf16x8*)(Bh + r*64 + SW(r,cb)) = *(const bf16x8*)(pwh + (size_t)(n0+r)*768 + kb + cb*8);
        }
        __syncthreads();
        #pragma unroll
        for (int ks = 0; ks < 2; ++ks){
            bf16x8 af[4], bfr[2];
            #pragma unroll
            for (int mt = 0; mt < 4; ++mt){
                int r = wm + mt*16 + lm, cb = lg + 4*ks;
                af[mt] = *(const bf16x8*)(Ah + r*64 + SW(r,cb));
            }
            #pragma unroll
            for (int nt = 0; nt < 2; ++nt){
                int r = wn + nt*16 + lm, cb = lg + 4*ks;
                bfr[nt] = *(const bf16x8*)(Bh + r*64 + SW(r,cb));
            }
            #pragma unroll
            for (int mt = 0; mt < 4; ++mt)
            #pragma unroll
            for (int nt = 0; nt < 2; ++nt)
                acc[mt][nt] = __builtin_amdgcn_mfma_f32_16x16x32_bf16(af[mt], bfr[nt], acc[mt][nt], 0,0,0);
        }
        __syncthreads();
    }
    #pragma unroll
    for (int mt = 0; mt < 4; ++mt)
    #pragma unroll
    for (int nt = 0; nt < 2; ++nt)
    #pragma unroll
    for (int rr = 0; rr < 4; ++rr){
        int grow = m0 + wm + mt*16 + lg*4 + rr;
        int gcol = n0 + wn + nt*16 + lm;
        size_t o = (size_t)grow*768 + gcol;
        out[o] = acc[mt][nt][rr] + pb[gcol] + xres[o];
    }
}

// ---------------- LayerNorm (in-place on out) ----------------
__global__ __launch_bounds__(256) void k_ln(float* __restrict__ out, const float* __restrict__ gamma,
                                            const float* __restrict__ beta){
    const int tid = threadIdx.x, lane = tid & 63, wid = tid >> 6;
    float* p = out + (size_t)blockIdx.x * 768;
    float v[3], s = 0.f, s2 = 0.f;
    #pragma unroll
    for (int j = 0; j < 3; ++j){ v[j] = p[tid + j*256]; s += v[j]; s2 += v[j]*v[j]; }
    #pragma unroll
    for (int mm = 1; mm < 64; mm <<= 1){ s += __shfl_xor(s, mm, 64); s2 += __shfl_xor(s2, mm, 64); }
    __shared__ float red[8];
    if (lane == 0){ red[wid] = s; red[4 + wid] = s2; }
    __syncthreads();
    s  = red[0] + red[1] + red[2] + red[3];
    s2 = red[4] + red[5] + red[6] + red[7];
    const float mu  = s * (1.0f/768.0f);
    const float var = s2 * (1.0f/768.0f) - mu*mu;
    const float inv = rsqrtf(var + 1e-5f);
    #pragma unroll
    for (int j = 0; j < 3; ++j){
        int c = tid + j*256;
        p[c] = (v[j] - mu) * inv * gamma[c] + beta[c];
    }
}

extern "C" void kernel_launch(void* const* d_in, const int* in_sizes, int n_in,
                              void* d_out, int out_size, void* d_ws, size_t ws_size,
                              hipStream_t stream){
    const float* x      = (const float*)d_in[0];
    const float* qkv_w  = (const float*)d_in[1];
    const float* proj_w = (const float*)d_in[2];
    const float* pb     = (const float*)d_in[3];
    const float* gamma  = (const float*)d_in[4];
    const float* beta   = (const float*)d_in[5];
    float* out = (float*)d_out;

    constexpr size_t SZ_X   = 8192ull * 768;
    constexpr size_t SZ_W   = 2304ull * 768;
    constexpr size_t SZ_PW  = 768ull * 768;
    constexpr size_t TOTAL  = 5*SZ_X + SZ_W + SZ_PW;
    if (ws_size < TOTAL * sizeof(u16)) return;

    u16* ws  = (u16*)d_ws;
    u16* xf  = ws;
    u16* wf  = xf  + SZ_X;
    u16* pwh = wf  + SZ_W;
    u16* qf  = pwh + SZ_PW;
    u16* kf  = qf  + SZ_X;
    u16* vt  = kf  + SZ_X;
    u16* x1h = vt  + SZ_X;

    k_prep<<<8448, 256, 0, stream>>>((const float4*)x, (const float4*)qkv_w, (const float4*)proj_w,
                                     xf, wf, pwh);
    k_qkv <<<dim3(18, 64), 256, 0, stream>>>(xf, wf, qf, kf, vt);
    k_attn<<<dim3(32, 48), 256, 0, stream>>>(qf, kf, vt, x1h);
    k_proj<<<dim3(12, 64), 256, 0, stream>>>(x1h, pwh, pb, x, out);
    k_ln  <<<8192, 256, 0, stream>>>(out, gamma, beta);
}